// Round 8
// baseline (822.772 us; speedup 1.0000x reference)
//
#include <hip/hip_runtime.h>

// RNN-T joint: log_softmax(fc2(tanh(fc1(cat(enc,dec))))), fused.
// B=4, M=256, N=128, D=512, C=1024, JOINT=1024.
// ws: heb f32 [1024][512] (he+b1) | hdb bf16 [512][512] | w2p bf16 frag-packed
//
// R8 = R6 persistent structure + R7's nontemporal stores.
// R6 failed because the cached store stream evicted w2p from L2 every gen
// (B-loads -> HBM, 900cyc, 1-deep prefetch = serial). nt stores keep
// w2p+heb+hdb L2-resident. Persistent 16-wave block, 8 gens of 64 rows:
// no endpgm store-drain tail; stores retire under the next gen's K-loop.

typedef __attribute__((ext_vector_type(8))) __bf16 bf16x8;
typedef __attribute__((ext_vector_type(8))) unsigned short u16x8;
typedef __attribute__((ext_vector_type(4))) float f32x4;

__device__ __forceinline__ float tanh_fast(float x) {
    float e = __expf(2.0f * x);
    return 1.0f - 2.0f / (e + 1.0f);
}
__device__ __forceinline__ float bf2f(unsigned short u) {
    return __builtin_bit_cast(float, (unsigned)u << 16);
}
__device__ __forceinline__ unsigned short f2bf(float f) {
    return __builtin_bit_cast(unsigned short, (__bf16)f);
}

// k_prep-only LDS swizzle
__device__ __forceinline__ int swz(int row, int kbyte) {
    return row * 1024 + (kbyte ^ ((row & 7) << 4));
}

__device__ __forceinline__ bf16x8 cvt8(float4 a, float4 b) {
    bf16x8 r;
    r[0] = (__bf16)a.x; r[1] = (__bf16)a.y; r[2] = (__bf16)a.z; r[3] = (__bf16)a.w;
    r[4] = (__bf16)b.x; r[5] = (__bf16)b.y; r[6] = (__bf16)b.z; r[7] = (__bf16)b.w;
    return r;
}

// ---------------------------------------------------------------------------
// Prep (validated R3/R5/R7): blocks 0..15 -> heb = enc@w1enc^T + b1 (f32),
// 16..23 -> hdb = bf16(dec@w1dec^T), 24..39 -> w2 -> w2p (frag order:
// chunk = (ctile*16 + kt)*64 + lg*16 + lr, 8 bf16 each).
// ---------------------------------------------------------------------------
__global__ __launch_bounds__(512) void k_prep(
    const float* __restrict__ enc, const float* __restrict__ dec,
    const float* __restrict__ w1, const float* __restrict__ b1,
    const float* __restrict__ w2,
    float* __restrict__ heb, unsigned short* __restrict__ hdb,
    unsigned short* __restrict__ w2p)
{
    const int bid = blockIdx.x, tid = threadIdx.x;

    if (bid >= 24) {  // pack w2 -> w2p
        int t = (bid - 24) * 512 + tid;
        #pragma unroll
        for (int i = 0; i < 8; ++i) {
            int p = t + i * 8192;
            int c = p >> 6, kc = p & 63;
            const float4* s = (const float4*)(w2 + c * 512 + kc * 8);
            float4 a = s[0], bq = s[1];
            u16x8 o;
            o[0] = f2bf(a.x);  o[1] = f2bf(a.y);  o[2] = f2bf(a.z);  o[3] = f2bf(a.w);
            o[4] = f2bf(bq.x); o[5] = f2bf(bq.y); o[6] = f2bf(bq.z); o[7] = f2bf(bq.w);
            int kt = kc >> 2, lg = kc & 3;
            int chunk = ((c >> 4) * 16 + kt) * 64 + lg * 16 + (c & 15);
            *(u16x8*)(w2p + chunk * 8) = o;
        }
        return;
    }

    __shared__ uint4 ldsq[4096];
    char* lds = (char*)ldsq;

    const int r0 = (bid < 16 ? bid : bid - 16) * 64;
    const float* src = (bid < 16 ? enc : dec) + r0 * 512;
    const float* wsrc = w1 + (bid < 16 ? 0 : 512);

    const int lane = tid & 63, wid = tid >> 6;
    #pragma unroll
    for (int j = 0; j < 8; j++) {
        int row = wid * 8 + j;
        const float4* p = (const float4*)(src + row * 512 + lane * 8);
        *(bf16x8*)(lds + swz(row, lane * 16)) = cvt8(p[0], p[1]);
    }
    __syncthreads();

    const int lr = lane & 15, lg = lane >> 4;
    f32x4 acc[4][4];
    #pragma unroll
    for (int rt = 0; rt < 4; rt++)
        #pragma unroll
        for (int ct = 0; ct < 4; ct++)
            acc[rt][ct] = f32x4{0.f, 0.f, 0.f, 0.f};

    #pragma unroll 1
    for (int ks = 0; ks < 512; ks += 32) {
        bf16x8 af[4];
        #pragma unroll
        for (int rt = 0; rt < 4; rt++)
            af[rt] = *(const bf16x8*)(lds + swz(rt * 16 + lr, ks * 2 + lg * 16));
        #pragma unroll
        for (int ct = 0; ct < 4; ct++) {
            int col = wid * 64 + ct * 16 + lr;
            const float4* wp = (const float4*)(wsrc + col * 1024 + ks + lg * 8);
            bf16x8 bfr = cvt8(wp[0], wp[1]);
            #pragma unroll
            for (int rt = 0; rt < 4; rt++)
                acc[rt][ct] = __builtin_amdgcn_mfma_f32_16x16x32_bf16(af[rt], bfr, acc[rt][ct], 0, 0, 0);
        }
    }

    if (bid < 16) {
        float b1v[4];
        #pragma unroll
        for (int ct = 0; ct < 4; ct++) b1v[ct] = b1[wid * 64 + ct * 16 + lr];
        #pragma unroll
        for (int rt = 0; rt < 4; rt++)
            #pragma unroll
            for (int ct = 0; ct < 4; ct++)
                #pragma unroll
                for (int reg = 0; reg < 4; reg++)
                    heb[(r0 + rt * 16 + lg * 4 + reg) * 512 + wid * 64 + ct * 16 + lr] =
                        acc[rt][ct][reg] + b1v[ct];
    } else {
        #pragma unroll
        for (int rt = 0; rt < 4; rt++)
            #pragma unroll
            for (int ct = 0; ct < 4; ct++)
                #pragma unroll
                for (int reg = 0; reg < 4; reg++)
                    hdb[(r0 + rt * 16 + lg * 4 + reg) * 512 + wid * 64 + ct * 16 + lr] =
                        f2bf(acc[rt][ct][reg]);
    }
}

// ---------------------------------------------------------------------------
// Stage gen g (64 rows x 512 k) as tanh(heb+hd) bf16 into ldbuf, frag-linear:
// region (RT*16+kt)*64 chunks; lane chunk = (row lr, kslice lg). Wave w covers
// row-tile RT=w>>2, kts (w&3)*4..+3. Conflict-free 1KB/wave ds_writes.
// g = b*512 + m*2 + nhalf.
// ---------------------------------------------------------------------------
__device__ __forceinline__ void stage_tile(
    int g, char* ldbuf, const float* heb, const unsigned short* hdb,
    int w, int lane, int lr, int lg)
{
    const int RT = w >> 2, kt0 = (w & 3) * 4;
    const unsigned short* hb =
        hdb + (size_t)((g >> 9) * 128 + (g & 1) * 64 + RT * 16 + lr) * 512 + lg * 8;
    const float* ep = heb + (size_t)(g >> 1) * 512 + lg * 8;
    char* ld = ldbuf + (RT * 16 * 64 + lane) * 16;
    #pragma unroll
    for (int it = 0; it < 4; ++it) {
        int kt = kt0 + it;
        u16x8 hv = *(const u16x8*)(hb + kt * 32);
        float4 e0 = *(const float4*)(ep + kt * 32);
        float4 e1 = *(const float4*)(ep + kt * 32 + 4);
        bf16x8 xo;
        xo[0] = (__bf16)tanh_fast(bf2f(hv[0]) + e0.x);
        xo[1] = (__bf16)tanh_fast(bf2f(hv[1]) + e0.y);
        xo[2] = (__bf16)tanh_fast(bf2f(hv[2]) + e0.z);
        xo[3] = (__bf16)tanh_fast(bf2f(hv[3]) + e0.w);
        xo[4] = (__bf16)tanh_fast(bf2f(hv[4]) + e1.x);
        xo[5] = (__bf16)tanh_fast(bf2f(hv[5]) + e1.y);
        xo[6] = (__bf16)tanh_fast(bf2f(hv[6]) + e1.z);
        xo[7] = (__bf16)tanh_fast(bf2f(hv[7]) + e1.w);
        *(bf16x8*)(ld + kt * 1024) = xo;
    }
}

// ---------------------------------------------------------------------------
// Main: persistent block = 16 waves, 8 gens of 64 rows x 1024 classes.
// Swapped MFMA (w2 = A, hid = B): lane holds (row n = rt*16+lr,
// classes (w*4+ct)*16 + lg*4 + 0..3) -> in-lane softmax, nt float4 stores.
// One barrier per gen; hid LDS double-buffered; red buffers by parity.
// ---------------------------------------------------------------------------
__global__ __launch_bounds__(1024, 4) void k_main(
    const float* __restrict__ heb, const unsigned short* __restrict__ hdb,
    const float* __restrict__ b2, const unsigned short* __restrict__ w2p,
    float* __restrict__ out)
{
    __shared__ uint4 ldsq[2][4096];        // 2 x 64 KB hid buffers
    __shared__ float redm[2][64][16];      // per-parity row-max partials
    __shared__ float reds[2][64][16];      // per-parity row-sumexp partials

    const int bid = blockIdx.x, tid = threadIdx.x;
    const int lane = tid & 63, w = tid >> 6, lr = lane & 15, lg = lane >> 4;

    const char* pw = (const char*)w2p + (w << 16) + (lane << 4);

    stage_tile(bid * 8, (char*)&ldsq[0][0], heb, hdb, w, lane, lr, lg);
    __syncthreads();

    #pragma unroll 1
    for (int j = 0; j < 8; ++j) {
        const int g = bid * 8 + j, s = j & 1;
        const char* la = (const char*)&ldsq[s][0] + (lane << 4);

        // ---- K-loop: w2 (A) reg-double-buffered from L2, hid (B) from LDS ----
        f32x4 acc[4][4];
        #pragma unroll
        for (int rt = 0; rt < 4; rt++)
            #pragma unroll
            for (int ct = 0; ct < 4; ct++)
                acc[rt][ct] = f32x4{0.f, 0.f, 0.f, 0.f};

        bf16x8 aw[2][4];
        #pragma unroll
        for (int ct = 0; ct < 4; ct++)
            aw[0][ct] = *(const bf16x8*)(pw + ct * 16384);

        #pragma unroll
        for (int kt = 0; kt < 16; ++kt) {
            if (kt < 15) {
                #pragma unroll
                for (int ct = 0; ct < 4; ct++)
                    aw[(kt + 1) & 1][ct] = *(const bf16x8*)(pw + ct * 16384 + (kt + 1) * 1024);
            }
            bf16x8 h[4];
            #pragma unroll
            for (int rt = 0; rt < 4; rt++)
                h[rt] = *(const bf16x8*)(la + (rt * 16 + kt) * 1024);
            __builtin_amdgcn_s_setprio(1);
            #pragma unroll
            for (int ct = 0; ct < 4; ct++)
                #pragma unroll
                for (int rt = 0; rt < 4; rt++)
                    acc[rt][ct] = __builtin_amdgcn_mfma_f32_16x16x32_bf16(
                        aw[kt & 1][ct], h[rt], acc[rt][ct], 0, 0, 0);
            __builtin_amdgcn_s_setprio(0);
        }

        // ---- stage next gen into the other LDS buffer (hides under K tail) ----
        if (j < 7)
            stage_tile(g + 1, (char*)&ldsq[s ^ 1][0], heb, hdb, w, lane, lr, lg);

        // ---- +b2 ----
        #pragma unroll
        for (int ct = 0; ct < 4; ct++) {
            float4 bq = *(const float4*)(b2 + (w * 4 + ct) * 16 + lg * 4);
            #pragma unroll
            for (int rt = 0; rt < 4; rt++) {
                acc[rt][ct][0] += bq.x; acc[rt][ct][1] += bq.y;
                acc[rt][ct][2] += bq.z; acc[rt][ct][3] += bq.w;
            }
        }

        // ---- per-wave online (max, sumexp) per row; merge across lg ----
        #pragma unroll
        for (int rt = 0; rt < 4; rt++) {
            float pm[4];
            #pragma unroll
            for (int ct = 0; ct < 4; ct++)
                pm[ct] = fmaxf(fmaxf(acc[rt][ct][0], acc[rt][ct][1]),
                               fmaxf(acc[rt][ct][2], acc[rt][ct][3]));
            float m = fmaxf(fmaxf(pm[0], pm[1]), fmaxf(pm[2], pm[3]));
            float sv = 0.f;
            #pragma unroll
            for (int ct = 0; ct < 4; ct++) {
                sv += __expf(acc[rt][ct][0] - m);
                sv += __expf(acc[rt][ct][1] - m);
                sv += __expf(acc[rt][ct][2] - m);
                sv += __expf(acc[rt][ct][3] - m);
            }
            float mo = __shfl_xor(m, 16), so = __shfl_xor(sv, 16);
            float mn = fmaxf(m, mo);
            sv = sv * __expf(m - mn) + so * __expf(mo - mn);
            m = mn;
            mo = __shfl_xor(m, 32); so = __shfl_xor(sv, 32);
            mn = fmaxf(m, mo);
            sv = sv * __expf(m - mn) + so * __expf(mo - mn);
            m = mn;
            if (lg == 0) {
                redm[s][rt * 16 + lr][w] = m;
                reds[s][rt * 16 + lr][w] = sv;
            }
        }
        __syncthreads();

        // ---- combine 16 wave-partials -> logZ; nt-store float4s ----
        // two-pass over LDS to keep live-register count low
        const size_t rowbase = (size_t)g * 64;
        #pragma unroll
        for (int rt = 0; rt < 4; rt++) {
            int r = rt * 16 + lr;
            const float4* mp = (const float4*)&redm[s][r][0];
            const float4* sp = (const float4*)&reds[s][r][0];
            // pass 1: global max
            float M;
            {
                float4 m0 = mp[0], m1 = mp[1];
                float a0 = fmaxf(fmaxf(m0.x, m0.y), fmaxf(m0.z, m0.w));
                float a1 = fmaxf(fmaxf(m1.x, m1.y), fmaxf(m1.z, m1.w));
                float4 m2 = mp[2], m3 = mp[3];
                float a2 = fmaxf(fmaxf(m2.x, m2.y), fmaxf(m2.z, m2.w));
                float a3 = fmaxf(fmaxf(m3.x, m3.y), fmaxf(m3.z, m3.w));
                M = fmaxf(fmaxf(a0, a1), fmaxf(a2, a3));
            }
            // pass 2: exp-weighted sum (re-read LDS)
            float S = 0.f;
            #pragma unroll
            for (int q = 0; q < 4; q++) {
                float4 mq = mp[q], sq = sp[q];
                S += sq.x * __expf(mq.x - M) + sq.y * __expf(mq.y - M)
                   + sq.z * __expf(mq.z - M) + sq.w * __expf(mq.w - M);
            }
            float logZ = M + __logf(S);

            float* orow = out + (rowbase + r) * 1024 + lg * 4;
            #pragma unroll
            for (int ct = 0; ct < 4; ct++) {
                f32x4 v = acc[rt][ct];
                f32x4 o;
                o[0] = v[0] - logZ; o[1] = v[1] - logZ;
                o[2] = v[2] - logZ; o[3] = v[3] - logZ;
                __builtin_nontemporal_store(o, (f32x4*)(orow + (w * 4 + ct) * 16));
            }
        }
    }
}

extern "C" void kernel_launch(void* const* d_in, const int* in_sizes, int n_in,
                              void* d_out, int out_size, void* d_ws, size_t ws_size,
                              hipStream_t stream) {
    const float* enc = (const float*)d_in[0];
    const float* dec = (const float*)d_in[1];
    const float* w1  = (const float*)d_in[2];
    const float* b1  = (const float*)d_in[3];
    const float* w2  = (const float*)d_in[4];
    const float* b2  = (const float*)d_in[5];

    float* heb = (float*)d_ws;                                   // 2 MB
    unsigned short* hdb = (unsigned short*)(heb + 1024 * 512);   // 0.5 MB
    unsigned short* w2p = hdb + 512 * 512;                       // 1 MB

    k_prep<<<40, 512, 0, stream>>>(enc, dec, w1, b1, w2, heb, hdb, w2p);
    k_main<<<256, 1024, 0, stream>>>(heb, hdb, b2, w2p, (float*)d_out);
}

// Round 9
// 309.563 us; speedup vs baseline: 2.6578x; 2.6578x over previous
//
#include <hip/hip_runtime.h>

// RNN-T joint: log_softmax(fc2(tanh(fc1(cat(enc,dec))))), fused.
// B=4, M=256, N=128, D=512, C=1024, JOINT=1024.
// ws: heb f32 [1024][512] (he+b1) | hdb bf16 [512][512] | w2p bf16 frag-packed
//
// R9 = R8 without persistence. R6/R8's persistent loops died of REGISTER
// SPILLS (VGPR pinned at the 128-cap, ~450 MB scratch round-trip visible in
// FETCH/WRITE). One 64-row generation per block needs only ~60 VGPR (R3-
// proven). 64-row blocks halve L2 B-traffic vs R7's 32-row (4->2 GB).
// Keeps: swapped MFMA epilogue (R5), nt stores + XCD swizzle (R7).

typedef __attribute__((ext_vector_type(8))) __bf16 bf16x8;
typedef __attribute__((ext_vector_type(8))) unsigned short u16x8;
typedef __attribute__((ext_vector_type(4))) float f32x4;

__device__ __forceinline__ float tanh_fast(float x) {
    float e = __expf(2.0f * x);
    return 1.0f - 2.0f / (e + 1.0f);
}
__device__ __forceinline__ float bf2f(unsigned short u) {
    return __builtin_bit_cast(float, (unsigned)u << 16);
}
__device__ __forceinline__ unsigned short f2bf(float f) {
    return __builtin_bit_cast(unsigned short, (__bf16)f);
}

// k_prep-only LDS swizzle
__device__ __forceinline__ int swz(int row, int kbyte) {
    return row * 1024 + (kbyte ^ ((row & 7) << 4));
}

__device__ __forceinline__ bf16x8 cvt8(float4 a, float4 b) {
    bf16x8 r;
    r[0] = (__bf16)a.x; r[1] = (__bf16)a.y; r[2] = (__bf16)a.z; r[3] = (__bf16)a.w;
    r[4] = (__bf16)b.x; r[5] = (__bf16)b.y; r[6] = (__bf16)b.z; r[7] = (__bf16)b.w;
    return r;
}

// ---------------------------------------------------------------------------
// Prep (validated R3..R7): blocks 0..15 -> heb = enc@w1enc^T + b1 (f32),
// 16..23 -> hdb = bf16(dec@w1dec^T), 24..39 -> w2 -> w2p (frag order:
// chunk = (ctile*16 + kt)*64 + lg*16 + lr, 8 bf16 each).
// ---------------------------------------------------------------------------
__global__ __launch_bounds__(512) void k_prep(
    const float* __restrict__ enc, const float* __restrict__ dec,
    const float* __restrict__ w1, const float* __restrict__ b1,
    const float* __restrict__ w2,
    float* __restrict__ heb, unsigned short* __restrict__ hdb,
    unsigned short* __restrict__ w2p)
{
    const int bid = blockIdx.x, tid = threadIdx.x;

    if (bid >= 24) {  // pack w2 -> w2p
        int t = (bid - 24) * 512 + tid;
        #pragma unroll
        for (int i = 0; i < 8; ++i) {
            int p = t + i * 8192;
            int c = p >> 6, kc = p & 63;
            const float4* s = (const float4*)(w2 + c * 512 + kc * 8);
            float4 a = s[0], bq = s[1];
            u16x8 o;
            o[0] = f2bf(a.x);  o[1] = f2bf(a.y);  o[2] = f2bf(a.z);  o[3] = f2bf(a.w);
            o[4] = f2bf(bq.x); o[5] = f2bf(bq.y); o[6] = f2bf(bq.z); o[7] = f2bf(bq.w);
            int kt = kc >> 2, lg = kc & 3;
            int chunk = ((c >> 4) * 16 + kt) * 64 + lg * 16 + (c & 15);
            *(u16x8*)(w2p + chunk * 8) = o;
        }
        return;
    }

    __shared__ uint4 ldsq[4096];
    char* lds = (char*)ldsq;

    const int r0 = (bid < 16 ? bid : bid - 16) * 64;
    const float* src = (bid < 16 ? enc : dec) + r0 * 512;
    const float* wsrc = w1 + (bid < 16 ? 0 : 512);

    const int lane = tid & 63, wid = tid >> 6;
    #pragma unroll
    for (int j = 0; j < 8; j++) {
        int row = wid * 8 + j;
        const float4* p = (const float4*)(src + row * 512 + lane * 8);
        *(bf16x8*)(lds + swz(row, lane * 16)) = cvt8(p[0], p[1]);
    }
    __syncthreads();

    const int lr = lane & 15, lg = lane >> 4;
    f32x4 acc[4][4];
    #pragma unroll
    for (int rt = 0; rt < 4; rt++)
        #pragma unroll
        for (int ct = 0; ct < 4; ct++)
            acc[rt][ct] = f32x4{0.f, 0.f, 0.f, 0.f};

    #pragma unroll 1
    for (int ks = 0; ks < 512; ks += 32) {
        bf16x8 af[4];
        #pragma unroll
        for (int rt = 0; rt < 4; rt++)
            af[rt] = *(const bf16x8*)(lds + swz(rt * 16 + lr, ks * 2 + lg * 16));
        #pragma unroll
        for (int ct = 0; ct < 4; ct++) {
            int col = wid * 64 + ct * 16 + lr;
            const float4* wp = (const float4*)(wsrc + col * 1024 + ks + lg * 8);
            bf16x8 bfr = cvt8(wp[0], wp[1]);
            #pragma unroll
            for (int rt = 0; rt < 4; rt++)
                acc[rt][ct] = __builtin_amdgcn_mfma_f32_16x16x32_bf16(af[rt], bfr, acc[rt][ct], 0, 0, 0);
        }
    }

    if (bid < 16) {
        float b1v[4];
        #pragma unroll
        for (int ct = 0; ct < 4; ct++) b1v[ct] = b1[wid * 64 + ct * 16 + lr];
        #pragma unroll
        for (int rt = 0; rt < 4; rt++)
            #pragma unroll
            for (int ct = 0; ct < 4; ct++)
                #pragma unroll
                for (int reg = 0; reg < 4; reg++)
                    heb[(r0 + rt * 16 + lg * 4 + reg) * 512 + wid * 64 + ct * 16 + lr] =
                        acc[rt][ct][reg] + b1v[ct];
    } else {
        #pragma unroll
        for (int rt = 0; rt < 4; rt++)
            #pragma unroll
            for (int ct = 0; ct < 4; ct++)
                #pragma unroll
                for (int reg = 0; reg < 4; reg++)
                    hdb[(r0 + rt * 16 + lg * 4 + reg) * 512 + wid * 64 + ct * 16 + lr] =
                        f2bf(acc[rt][ct][reg]);
    }
}

// ---------------------------------------------------------------------------
// Main: block = one generation of 64 rows (g = b*512 + m*2 + nhalf) x 1024
// classes, 16 waves. Swapped MFMA (w2 = A from L2, hid = B from LDS):
// lane holds (row n = rt*16+lr, classes (w*4+ct)*16 + lg*4 + 0..3).
// In-lane softmax partials, one barrier, nt float4 stores.
// ---------------------------------------------------------------------------
__global__ __launch_bounds__(1024, 4) void k_main(
    const float* __restrict__ heb, const unsigned short* __restrict__ hdb,
    const float* __restrict__ b2, const unsigned short* __restrict__ w2p,
    float* __restrict__ out)
{
    __shared__ uint4 ldsq[4096];           // 64 KB hid tile (4 rt x 16 kt x 1KB)
    __shared__ float redm[64][16];         // row-max partials
    __shared__ float reds[64][16];         // row-sumexp partials
    char* lds = (char*)ldsq;

    // XCD-bijective remap (2048 % 8 == 0): 256 consecutive gens per XCD.
    const int g = ((blockIdx.x & 7) << 8) | (blockIdx.x >> 3);
    const int tid = threadIdx.x;
    const int lane = tid & 63, w = tid >> 6, lr = lane & 15, lg = lane >> 4;

    // ---- stage hid = tanh(heb + hd) bf16, fragment-linear ----
    // wave w: RT = w>>2, kts (w&3)*4..+3; lane chunk = (row lr, kslice lg)
    {
        const int RT = w >> 2, kt0 = (w & 3) * 4;
        const unsigned short* hb =
            hdb + (size_t)((g >> 9) * 128 + (g & 1) * 64 + RT * 16 + lr) * 512 + lg * 8;
        const float* ep = heb + (size_t)(g >> 1) * 512 + lg * 8;
        char* ld = lds + (RT * 16 * 64 + lane) * 16;
        #pragma unroll
        for (int it = 0; it < 4; ++it) {
            int kt = kt0 + it;
            u16x8 hv = *(const u16x8*)(hb + kt * 32);
            float4 e0 = *(const float4*)(ep + kt * 32);
            float4 e1 = *(const float4*)(ep + kt * 32 + 4);
            bf16x8 xo;
            xo[0] = (__bf16)tanh_fast(bf2f(hv[0]) + e0.x);
            xo[1] = (__bf16)tanh_fast(bf2f(hv[1]) + e0.y);
            xo[2] = (__bf16)tanh_fast(bf2f(hv[2]) + e0.z);
            xo[3] = (__bf16)tanh_fast(bf2f(hv[3]) + e0.w);
            xo[4] = (__bf16)tanh_fast(bf2f(hv[4]) + e1.x);
            xo[5] = (__bf16)tanh_fast(bf2f(hv[5]) + e1.y);
            xo[6] = (__bf16)tanh_fast(bf2f(hv[6]) + e1.z);
            xo[7] = (__bf16)tanh_fast(bf2f(hv[7]) + e1.w);
            *(bf16x8*)(ld + kt * 1024) = xo;
        }
    }
    __syncthreads();

    // ---- K-loop: w2 (A) reg-double-buffered from L2, hid (B) from LDS ----
    const char* pw = (const char*)w2p + (w << 16) + (lane << 4);
    const char* la = lds + (lane << 4);

    f32x4 acc[4][4];
    #pragma unroll
    for (int rt = 0; rt < 4; rt++)
        #pragma unroll
        for (int ct = 0; ct < 4; ct++)
            acc[rt][ct] = f32x4{0.f, 0.f, 0.f, 0.f};

    bf16x8 aw[2][4];
    #pragma unroll
    for (int ct = 0; ct < 4; ct++)
        aw[0][ct] = *(const bf16x8*)(pw + ct * 16384);

    #pragma unroll
    for (int kt = 0; kt < 16; ++kt) {
        if (kt < 15) {
            #pragma unroll
            for (int ct = 0; ct < 4; ct++)
                aw[(kt + 1) & 1][ct] = *(const bf16x8*)(pw + ct * 16384 + (kt + 1) * 1024);
        }
        bf16x8 h[4];
        #pragma unroll
        for (int rt = 0; rt < 4; rt++)
            h[rt] = *(const bf16x8*)(la + (rt * 16 + kt) * 1024);
        __builtin_amdgcn_s_setprio(1);
        #pragma unroll
        for (int ct = 0; ct < 4; ct++)
            #pragma unroll
            for (int rt = 0; rt < 4; rt++)
                acc[rt][ct] = __builtin_amdgcn_mfma_f32_16x16x32_bf16(
                    aw[kt & 1][ct], h[rt], acc[rt][ct], 0, 0, 0);
        __builtin_amdgcn_s_setprio(0);
    }

    // ---- +b2 ----
    #pragma unroll
    for (int ct = 0; ct < 4; ct++) {
        float4 bq = *(const float4*)(b2 + (w * 4 + ct) * 16 + lg * 4);
        #pragma unroll
        for (int rt = 0; rt < 4; rt++) {
            acc[rt][ct][0] += bq.x; acc[rt][ct][1] += bq.y;
            acc[rt][ct][2] += bq.z; acc[rt][ct][3] += bq.w;
        }
    }

    // ---- per-wave online (max, sumexp) per row; merge across lg ----
    #pragma unroll
    for (int rt = 0; rt < 4; rt++) {
        float pm[4];
        #pragma unroll
        for (int ct = 0; ct < 4; ct++)
            pm[ct] = fmaxf(fmaxf(acc[rt][ct][0], acc[rt][ct][1]),
                           fmaxf(acc[rt][ct][2], acc[rt][ct][3]));
        float m = fmaxf(fmaxf(pm[0], pm[1]), fmaxf(pm[2], pm[3]));
        float sv = 0.f;
        #pragma unroll
        for (int ct = 0; ct < 4; ct++) {
            sv += __expf(acc[rt][ct][0] - m);
            sv += __expf(acc[rt][ct][1] - m);
            sv += __expf(acc[rt][ct][2] - m);
            sv += __expf(acc[rt][ct][3] - m);
        }
        float mo = __shfl_xor(m, 16), so = __shfl_xor(sv, 16);
        float mn = fmaxf(m, mo);
        sv = sv * __expf(m - mn) + so * __expf(mo - mn);
        m = mn;
        mo = __shfl_xor(m, 32); so = __shfl_xor(sv, 32);
        mn = fmaxf(m, mo);
        sv = sv * __expf(m - mn) + so * __expf(mo - mn);
        m = mn;
        if (lg == 0) {
            redm[rt * 16 + lr][w] = m;
            reds[rt * 16 + lr][w] = sv;
        }
    }
    __syncthreads();

    // ---- combine 16 wave-partials -> logZ; nt-store float4s ----
    const size_t rowbase = (size_t)g * 64;
    #pragma unroll
    for (int rt = 0; rt < 4; rt++) {
        int r = rt * 16 + lr;
        const float4* mp = (const float4*)&redm[r][0];
        const float4* sp = (const float4*)&reds[r][0];
        float M;
        {
            float4 m0 = mp[0], m1 = mp[1];
            float a0 = fmaxf(fmaxf(m0.x, m0.y), fmaxf(m0.z, m0.w));
            float a1 = fmaxf(fmaxf(m1.x, m1.y), fmaxf(m1.z, m1.w));
            float4 m2 = mp[2], m3 = mp[3];
            float a2 = fmaxf(fmaxf(m2.x, m2.y), fmaxf(m2.z, m2.w));
            float a3 = fmaxf(fmaxf(m3.x, m3.y), fmaxf(m3.z, m3.w));
            M = fmaxf(fmaxf(a0, a1), fmaxf(a2, a3));
        }
        float S = 0.f;
        #pragma unroll
        for (int q = 0; q < 4; q++) {
            float4 mq = mp[q], sq = sp[q];
            S += sq.x * __expf(mq.x - M) + sq.y * __expf(mq.y - M)
               + sq.z * __expf(mq.z - M) + sq.w * __expf(mq.w - M);
        }
        float logZ = M + __logf(S);

        float* orow = out + (rowbase + r) * 1024 + lg * 4;
        #pragma unroll
        for (int ct = 0; ct < 4; ct++) {
            f32x4 v = acc[rt][ct];
            f32x4 o;
            o[0] = v[0] - logZ; o[1] = v[1] - logZ;
            o[2] = v[2] - logZ; o[3] = v[3] - logZ;
            __builtin_nontemporal_store(o, (f32x4*)(orow + (w * 4 + ct) * 16));
        }
    }
}

extern "C" void kernel_launch(void* const* d_in, const int* in_sizes, int n_in,
                              void* d_out, int out_size, void* d_ws, size_t ws_size,
                              hipStream_t stream) {
    const float* enc = (const float*)d_in[0];
    const float* dec = (const float*)d_in[1];
    const float* w1  = (const float*)d_in[2];
    const float* b1  = (const float*)d_in[3];
    const float* w2  = (const float*)d_in[4];
    const float* b2  = (const float*)d_in[5];

    float* heb = (float*)d_ws;                                   // 2 MB
    unsigned short* hdb = (unsigned short*)(heb + 1024 * 512);   // 0.5 MB
    unsigned short* w2p = hdb + 512 * 512;                       // 1 MB

    k_prep<<<40, 512, 0, stream>>>(enc, dec, w1, b1, w2, heb, hdb, w2p);
    k_main<<<2048, 1024, 0, stream>>>(heb, hdb, b2, w2p, (float*)d_out);
}